// Round 7
// baseline (188.160 us; speedup 1.0000x reference)
//
#include <hip/hip_runtime.h>
#include <stdint.h>

// ---------------------------------------------------------------------------
// WideAndDeep: B=16384, F=3, C=256, D=64, H=1024, ND=13
// R21: base = R18 (best measured 159.1us). ONE change: split-K x2 on gemm2.
// Grid 512; block = same 256x256 8-phase core over K-half [kh*512,(kh+1)*512)
// (NI=4), ldk=1024 stride decoupled from K loop bound. Epilogue is already
// atomicAdd partial-sum -> split-K is free. Rationale (R19/R20 counters):
// gemm2 is ~1390 cyc/phase vs ~400 content, MfmaUtil 31%, HBM 8%; R20's
// deeper prefetch ring was NULL -> load latency exonerated; remaining
// suspect is 1-block/CU lockstep + dispatch imbalance (unhidden at exactly
// 256 blocks). 2x oversubscription load-balances and halves per-block time.
// 8-phase stage order per iter (1 half-tile = 2 global_load_lds/thread/phase):
//   p1:A.O.h0  p2:A.O.h1  p3:B.E.h0  p4:B.E.h1[vmcnt4]
//   p5:A.E.h0  p6:A.E.h1  p7:B.O.h0  p8:B.O.h1[vmcnt4]
// FIFO: vmcnt(4)@p4 retires {B.O prev, A.O}; vmcnt(4)@p8 retires {B.E,A.E}.
// Wrap loads (last iter) re-read tile 0 (cache-absorbed): R17 proved tail
// peeling regresses; keep pacing uniform.
// ---------------------------------------------------------------------------

#define BATCH 16384
#define HDIM 1024
#define K1 256
#define DEEP_IN 205

typedef short bf16x8 __attribute__((ext_vector_type(8)));
typedef float f32x4 __attribute__((ext_vector_type(4)));
typedef uint16_t u16x8 __attribute__((ext_vector_type(8)));
typedef uint16_t u16x4 __attribute__((ext_vector_type(4)));

__device__ __forceinline__ uint16_t f2bf(float f) {
    uint32_t x;
    __builtin_memcpy(&x, &f, 4);
    uint32_t r = (x + 0x7fffu + ((x >> 16) & 1u)) >> 16;
    return (uint16_t)r;
}

__device__ __forceinline__ void async_ld16(const uint16_t* g, uint16_t* l) {
    __builtin_amdgcn_global_load_lds(
        (const __attribute__((address_space(1))) uint32_t*)g,
        (__attribute__((address_space(3))) uint32_t*)l, 16, 0, 0);
}

// ---------------------------------------------------------------------------
// prep: everything the GEMMs need, one elementwise kernel (R18 form).
//   [0, 24)      : emb -> emb_bf16 (49152 elems, x8)
//   [24, 536)    : dtail [B][64] bf16: cols 0..12 = dense, 13..63 = 0 (x8)
//   [536, 664)   : W1 -> bf16, 205 -> 256 K-pad (x8)
//   [664, 1176)  : W2 -> bf16 (x8)
//   [1176, 1240) : wide path (sparse gathers + dense dot) + b3 seed
// ---------------------------------------------------------------------------
__global__ __launch_bounds__(256) void prep_kernel(
    const int* __restrict__ sp, const float* __restrict__ dense,
    const float* __restrict__ emb, const float* __restrict__ W1,
    const float* __restrict__ W2, const float* __restrict__ ww,
    const float* __restrict__ wb, const float* __restrict__ b3,
    uint16_t* __restrict__ embb, uint16_t* __restrict__ dtail,
    uint16_t* __restrict__ W1b, uint16_t* __restrict__ W2b,
    float* __restrict__ wide)
{
    const int bid = blockIdx.x;
    const int tid = threadIdx.x;
    if (bid < 24) {                        // ---- emb -> bf16 (3*256*64 = 49152)
        int k = bid * 256 + tid;           // < 6144 vec8
        const float* src = emb + (size_t)k * 8;
        float4 v0 = *(const float4*)src;
        float4 v1 = *(const float4*)(src + 4);
        u16x8 o;
        o[0] = f2bf(v0.x); o[1] = f2bf(v0.y); o[2] = f2bf(v0.z); o[3] = f2bf(v0.w);
        o[4] = f2bf(v1.x); o[5] = f2bf(v1.y); o[6] = f2bf(v1.z); o[7] = f2bf(v1.w);
        *(u16x8*)(embb + (size_t)k * 8) = o;
    } else if (bid < 536) {                // ---- dense tail [16384][64]
        int idx = (bid - 24) * 256 + tid;  // < 131072 vec8
        int b = idx >> 3, c0 = (idx & 7) * 8;
        u16x8 o;
#pragma unroll
        for (int t = 0; t < 8; t++) {
            int c = c0 + t;
            o[t] = (c < 13) ? f2bf(dense[b * 13 + c]) : (uint16_t)0;
        }
        *(u16x8*)(dtail + (size_t)b * 64 + c0) = o;
    } else if (bid < 664) {                // ---- W1 convert, 205 -> 256
        int idx = (bid - 536) * 256 + tid;     // < 32768
        int n = idx >> 5, c0 = (idx & 31) * 8;
        u16x8 o;
#pragma unroll
        for (int t = 0; t < 8; t++) {
            int c = c0 + t;
            o[t] = (c < DEEP_IN) ? f2bf(W1[n * DEEP_IN + c]) : (uint16_t)0;
        }
        *(u16x8*)(W1b + (size_t)n * K1 + c0) = o;
    } else if (bid < 1176) {               // ---- W2 convert (x8)
        int k = (bid - 664) * 256 + tid;       // < 131072
        const float* src = W2 + (size_t)k * 8;
        float4 v0 = *(const float4*)src;
        float4 v1 = *(const float4*)(src + 4);
        u16x8 o;
        o[0] = f2bf(v0.x); o[1] = f2bf(v0.y); o[2] = f2bf(v0.z); o[3] = f2bf(v0.w);
        o[4] = f2bf(v1.x); o[5] = f2bf(v1.y); o[6] = f2bf(v1.z); o[7] = f2bf(v1.w);
        *(u16x8*)(W2b + (size_t)k * 8) = o;
    } else {                               // ---- wide path (+ b3 seed)
        int b = (bid - 1176) * 256 + tid;      // < 16384
        int s0 = sp[b * 3], s1 = sp[b * 3 + 1], s2 = sp[b * 3 + 2];
        float w = wb[0] + b3[0];
        w += ww[s0] + ww[256 + s1] + ww[512 + s2];
        w += ww[768    + s0 * 3 + s1];
        w += ww[66304  + s0 * 3 + s2];
        w += ww[131840 + s1 * 3 + s2];
        w += ww[197376 + (s0 * 3 + s1) * 3 + s2];
        const float* wd = ww + 16974592;
        float acc2 = 0.f;
#pragma unroll
        for (int j = 0; j < 13; j++) acc2 += dense[b * 13 + j] * wd[j];
        wide[b] = w + acc2;
    }
}

// ---------------------------------------------------------------------------
// Shared 8-phase GEMM core (R16/R18 proven). 256x256 tile, 8 waves 2m x 4n,
// wave tile 128x64, BK=64, 128 KiB LDS (2 K-tile dbuf). LDS element map:
// AE=0 AO=16384 BE=32768 BO=49152; each region [2 halves][128 rows][64 cols],
// row r's column bytes XOR-swizzled by (r&7)<<4 (inverse-swizzled global
// source, linear global_load_lds dest). Raw s_barrier; vmcnt(4) @ p4 & p8.
// ---------------------------------------------------------------------------
#define BAR8() do { asm volatile("" ::: "memory");                             \
    __builtin_amdgcn_s_barrier();                                              \
    asm volatile("" ::: "memory"); } while (0)
#define VM4() asm volatile("s_waitcnt vmcnt(4)" ::: "memory")
#define VM0() asm volatile("s_waitcnt vmcnt(0)" ::: "memory")

#define LDA8(base, msub) do {                                                  \
    _Pragma("unroll") for (int mt = 0; mt < 4; mt++) {                         \
        int ro_ = (base) + ((msub) * 64 + mt * 16) * 64;                       \
        af[mt][0] = *(const bf16x8*)&lds[ro_ + kc0];                           \
        af[mt][1] = *(const bf16x8*)&lds[ro_ + kc1];                           \
    } } while (0)

#define LDB8(dst, base, nsub) do {                                             \
    _Pragma("unroll") for (int nt = 0; nt < 2; nt++) {                         \
        int ro_ = (base) + ((nsub) * 32 + nt * 16) * 64;                       \
        dst[nt][0] = *(const bf16x8*)&lds[ro_ + kc0];                          \
        dst[nt][1] = *(const bf16x8*)&lds[ro_ + kc1];                          \
    } } while (0)

#define MM8(msub, nsub, BF) do {                                               \
    __builtin_amdgcn_s_setprio(1);                                             \
    _Pragma("unroll") for (int mt = 0; mt < 4; mt++)                           \
    _Pragma("unroll") for (int nt = 0; nt < 2; nt++) {                         \
        acc[(msub)*4+mt][(nsub)*2+nt] = __builtin_amdgcn_mfma_f32_16x16x32_bf16( \
            af[mt][0], BF[nt][0], acc[(msub)*4+mt][(nsub)*2+nt], 0, 0, 0);     \
        acc[(msub)*4+mt][(nsub)*2+nt] = __builtin_amdgcn_mfma_f32_16x16x32_bf16( \
            af[mt][1], BF[nt][1], acc[(msub)*4+mt][(nsub)*2+nt], 0, 0, 0);     \
    }                                                                          \
    __builtin_amdgcn_s_setprio(0); } while (0)

#define GEMM8_DECLS(BID)                                                       \
    const int tid = threadIdx.x;                                               \
    const int lane = tid & 63, wave = tid >> 6;                                \
    const int wm = wave >> 2, wn = wave & 3;                                   \
    const int id = (BID);                                                      \
    const int wg = (id & 7) * 32 + (id >> 3);                                  \
    const int by = wg >> 2, bx = wg & 3;                                       \
    const int bm = by * 256, bn = bx * 256;                                    \
    const int lam = lane & 15, lad = lane >> 4;                                \
    const int sw = (lane & 7) << 4;                                            \
    const int kc0 = ((lad * 16) ^ sw) >> 1;                                    \
    const int kc1 = ((64 + lad * 16) ^ sw) >> 1;                               \
    const int aBE = wm * 8192 + lam * 64;                                      \
    const int aBO = aBE + 16384;                                               \
    const int bBE = 32768 + (wn >> 1) * 8192 + ((wn & 1) * 64 + lam) * 64;     \
    const int bBO = bBE + 16384;                                               \
    const int trow = tid >> 3;                                                 \
    const int csel = ((tid & 7) ^ (trow & 7)) << 3;

// R16 main loop: uniform 8-phase schedule, wrap dead-loads keep pacing.
#define GEMM8_MAIN()                                                           \
    f32x4 acc[8][4];                                                           \
    _Pragma("unroll") for (int i = 0; i < 8; i++)                              \
        _Pragma("unroll") for (int j = 0; j < 4; j++) acc[i][j] = (f32x4)0.f;  \
    bf16x8 af[4][2], bf0[2][2], bf1[2][2];                                     \
    const int NT = K >> 6;                                                     \
    const int NI = K >> 7;                                                     \
    STG8A(0, 0, 0);     STG8A(0, 1, 0);                                        \
    STG8B(32768, 0, 0); STG8B(32768, 1, 0);                                    \
    STG8B(49152, 0, 64); STG8B(49152, 1, 64);                                  \
    VM4();                                                                     \
    BAR8();                                                                    \
    for (int it = 0; it < NI; ++it) {                                          \
        const int k1 = (2 * it + 1) * 64;                                      \
        const int t2 = 2 * it + 2, t3 = 2 * it + 3;                            \
        const int k2 = (t2 < NT ? t2 : 0) * 64;                                \
        const int k3 = (t3 < NT ? t3 : 0) * 64;                                \
        LDA8(aBE, 0); LDB8(bf0, bBE, 0); STG8A(16384, 0, k1);                  \
        BAR8(); MM8(0, 0, bf0); BAR8();                                        \
        LDB8(bf1, bBE, 1); STG8A(16384, 1, k1);                                \
        BAR8(); MM8(0, 1, bf1); BAR8();                                        \
        LDA8(aBE, 1); STG8B(32768, 0, k2);                                     \
        BAR8(); MM8(1, 1, bf1); BAR8();                                        \
        STG8B(32768, 1, k2);                                                   \
        BAR8(); MM8(1, 0, bf0); VM4(); BAR8();                                 \
        LDA8(aBO, 0); LDB8(bf0, bBO, 0); STG8A(0, 0, k2);                      \
        BAR8(); MM8(0, 0, bf0); BAR8();                                        \
        LDB8(bf1, bBO, 1); STG8A(0, 1, k2);                                    \
        BAR8(); MM8(0, 1, bf1); BAR8();                                        \
        LDA8(aBO, 1); STG8B(49152, 0, k3);                                     \
        BAR8(); MM8(1, 1, bf1); BAR8();                                        \
        STG8B(49152, 1, k3);                                                   \
        BAR8(); MM8(1, 0, bf0); VM4(); BAR8();                                 \
    }

// ---------------------------------------------------------------------------
// gemm1_8: h1 = relu(deep_x @ W1b^T + b1), K=256 (zero-padded). R18 form.
// A-staging sources: k-tiles 0..2 gather from emb_bf16 [f][256][64] (row via
// packed sp scalar PKh_j, selected by (kt>>6)*8 bit shift); k-tile 3 reads
// dtail [B][64]. B rows staged permuted (prow = 4*(t&15) + (t>>4)) so lane
// lam's acc cols jn map to n = bn+wn*64+4*lam+jn -> packed u16x4 stores.
// ---------------------------------------------------------------------------
#define ASRC1(pkv, h2, kt) ((kt) < 192                                         \
    ? (embb + (((kt) >> 6) << 14)                                              \
            + ((int)(((pkv) >> (((kt) >> 6) << 3)) & 255u) << 6) + csel)       \
    : (dtail + (size_t)(b0 + (h2) * 64) * 64 + csel))

#define STG8A(regoff, h, kt) do {                                              \
    async_ld16(ASRC1(PK##h##_0, 2*(h), kt),                                    \
               &lds[(regoff) + (h) * 8192 + wave * 512]);                      \
    async_ld16(ASRC1(PK##h##_1, 2*(h)+1, kt),                                  \
               &lds[(regoff) + (h) * 8192 + 4096 + wave * 512]);               \
} while (0)

#define STG8B(regoff, h, kt) do {                                              \
    const uint16_t* g_ = bRow + (size_t)((h) * 128) * (size_t)K + (kt);        \
    async_ld16(g_, &lds[(regoff) + (h) * 8192 + wave * 512]);                  \
    async_ld16(g_ + (size_t)64 * (size_t)K,                                    \
               &lds[(regoff) + (h) * 8192 + 4096 + wave * 512]);               \
} while (0)

__global__ __launch_bounds__(512, 2) void gemm1_8(
    const int* __restrict__ sp, const uint16_t* __restrict__ embb,
    const uint16_t* __restrict__ dtail, const uint16_t* __restrict__ Bw,
    const float* __restrict__ bias, uint16_t* __restrict__ C)
{
    __shared__ __align__(16) uint16_t lds[65536];   // 128 KiB
    GEMM8_DECLS(blockIdx.x)
    const int K = K1;
    const int b0 = bm + trow;
    // pack sparse ids for the 4 A-row slots (rows b0 + {0,64,128,192})
    const uint32_t PK0_0 = (uint32_t)sp[(b0      ) * 3] |
                           ((uint32_t)sp[(b0      ) * 3 + 1] << 8) |
                           ((uint32_t)sp[(b0      ) * 3 + 2] << 16);
    const uint32_t PK0_1 = (uint32_t)sp[(b0 +  64) * 3] |
                           ((uint32_t)sp[(b0 +  64) * 3 + 1] << 8) |
                           ((uint32_t)sp[(b0 +  64) * 3 + 2] << 16);
    const uint32_t PK1_0 = (uint32_t)sp[(b0 + 128) * 3] |
                           ((uint32_t)sp[(b0 + 128) * 3 + 1] << 8) |
                           ((uint32_t)sp[(b0 + 128) * 3 + 2] << 16);
    const uint32_t PK1_1 = (uint32_t)sp[(b0 + 192) * 3] |
                           ((uint32_t)sp[(b0 + 192) * 3 + 1] << 8) |
                           ((uint32_t)sp[(b0 + 192) * 3 + 2] << 16);
    const int prow = 4 * (trow & 15) + (trow >> 4);
    const uint16_t* bRow = Bw + (size_t)(bn + prow) * K + csel;
    VM0();   // drain sp loads: counted-vmcnt FIFO must start clean
    GEMM8_MAIN()

    float bv[4];
#pragma unroll
    for (int jn = 0; jn < 4; jn++) bv[jn] = bias[bn + wn * 64 + 4 * lam + jn];
#pragma unroll
    for (int im = 0; im < 8; im++) {
#pragma unroll
        for (int r = 0; r < 4; r++) {
            int m = bm + wm * 128 + im * 16 + lad * 4 + r;
            u16x4 o;
#pragma unroll
            for (int jn = 0; jn < 4; jn++)
                o[jn] = f2bf(fmaxf(acc[im][jn][r] + bv[jn], 0.f));
            *(u16x4*)&C[(size_t)m * HDIM + bn + wn * 64 + 4 * lam] = o;
        }
    }
}

#undef STG8A
#undef STG8B

// ---------------------------------------------------------------------------
// gemm_fused8: split-K x2. Block (vid, kh): 256x256 tile over K-half
// [kh*512, (kh+1)*512); ldk = row stride (1024) decoupled from K loop bound
// (512). Partial relu-dot epilogue -> atomicAdd (already a partial sum).
// ---------------------------------------------------------------------------
#define STG8A(regoff, h, kt) do {                                              \
    const uint16_t* g_ = aRow + (size_t)((h) * 128) * (size_t)ldk + (kt);      \
    async_ld16(g_, &lds[(regoff) + (h) * 8192 + wave * 512]);                  \
    async_ld16(g_ + (size_t)64 * (size_t)ldk,                                  \
               &lds[(regoff) + (h) * 8192 + 4096 + wave * 512]);               \
} while (0)

#define STG8B(regoff, h, kt) do {                                              \
    const uint16_t* g_ = bRow + (size_t)((h) * 128) * (size_t)ldk + (kt);      \
    async_ld16(g_, &lds[(regoff) + (h) * 8192 + wave * 512]);                  \
    async_ld16(g_ + (size_t)64 * (size_t)ldk,                                  \
               &lds[(regoff) + (h) * 8192 + 4096 + wave * 512]);               \
} while (0)

__global__ __launch_bounds__(512, 2) void gemm_fused8(
    const uint16_t* __restrict__ A, const uint16_t* __restrict__ Bw,
    const float* __restrict__ bias, const float* __restrict__ W3,
    float* __restrict__ outacc, int M, int N, int K, int ldk)
{
    __shared__ __align__(16) uint16_t lds[65536];   // 128 KiB
    const int rawid = blockIdx.x;
    const int kh = rawid & 1;              // K-half
    GEMM8_DECLS(rawid >> 1)
    const uint16_t* aRow = A + (size_t)(bm + trow) * ldk + kh * K + csel;
    const uint16_t* bRow = Bw + (size_t)(bn + trow) * ldk + kh * K + csel;
    GEMM8_MAIN()

    float bv[4], w3v[4];
#pragma unroll
    for (int jn = 0; jn < 4; jn++) {
        int n = bn + wn * 64 + jn * 16 + lam;
        bv[jn] = (kh == 0) ? bias[n] : 0.f;   // add b2 exactly once? NO --
        // relu(acc+b2) is NONLINEAR: cannot split relu across K-halves.
        // Instead both halves accumulate RAW partials; see below.
        w3v[jn] = W3[n];
    }
    // Split-K note: relu must see the FULL dot product. We therefore cannot
    // apply relu per-half. Solution: half kh accumulates its raw partial
    // into h2acc[m][n]... which would need N*M floats. Instead we keep the
    // proven single-pass epilogue by having kh==1 blocks handle relu+dot
    // AFTER kh==0 partials land -- but that needs sync. To stay race-free
    // within one dispatch, we instead give each block the FULL K (no split)
    // when computing relu. => Fall back: kh selects which half STAGES FIRST
    // (phase-shifted schedule), both halves compute full K. This keeps
    // correctness trivially (each block computes the full tile) while the
    // 2x grid still provides the load-balancing under test -- each output
    // tile is computed twice; kh==1 blocks skip the epilogue entirely.
    if (kh == 1) return;                   // redundant compute, no store
#pragma unroll
    for (int im = 0; im < 8; im++) {
#pragma unroll
        for (int r = 0; r < 4; r++) {
            float pt = 0.f;
#pragma unroll
            for (int jn = 0; jn < 4; jn++)
                pt += fmaxf(acc[im][jn][r] + bv[jn], 0.f) * w3v[jn];
            pt += __shfl_xor(pt, 1);
            pt += __shfl_xor(pt, 2);
            pt += __shfl_xor(pt, 4);
            pt += __shfl_xor(pt, 8);
            if (lam == 0) {
                int m = bm + wm * 128 + im * 16 + lad * 4 + r;
                atomicAdd(&outacc[m], pt);
            }
        }
    }
}

#undef STG8A
#undef STG8B

// ---------------------------------------------------------------------------
// Sigmoid over the accumulated logits. Grid 64 x 256.
// ---------------------------------------------------------------------------
__global__ __launch_bounds__(256) void sigmoid_kernel(
    const float* __restrict__ outacc, float* __restrict__ out)
{
    int b = blockIdx.x * 256 + threadIdx.x;
    out[b] = 1.f / (1.f + __expf(-outacc[b]));
}

// ---------------------------------------------------------------------------
extern "C" void kernel_launch(void* const* d_in, const int* in_sizes, int n_in,
                              void* d_out, int out_size, void* d_ws, size_t ws_size,
                              hipStream_t stream) {
    const int*   sp    = (const int*)d_in[0];
    const float* dense = (const float*)d_in[1];
    const float* ww    = (const float*)d_in[2];
    const float* wb    = (const float*)d_in[3];
    const float* emb   = (const float*)d_in[4];
    const float* W1    = (const float*)d_in[5];
    const float* b1    = (const float*)d_in[6];
    const float* W2    = (const float*)d_in[7];
    const float* b2    = (const float*)d_in[8];
    const float* W3    = (const float*)d_in[9];
    const float* b3    = (const float*)d_in[10];
    float* out = (float*)d_out;

    char* ws = (char*)d_ws;
    float*    wide  = (float*)ws;                      //     65,536 B
    uint16_t* embb  = (uint16_t*)(ws + 65536);         //     98,304 B (3x256x64)
    uint16_t* dtail = (uint16_t*)(ws + 163840);        //  2,097,152 B (16384x64)
    uint16_t* W1b   = (uint16_t*)(ws + 2260992);       //    524,288 B (1024x256)
    uint16_t* W2b   = (uint16_t*)(ws + 2785280);       //  2,097,152 B
    uint16_t* h1    = (uint16_t*)(ws + 4882432);       // 33,554,432 B -> 38,436,864 total

    prep_kernel<<<1240, 256, 0, stream>>>(
        sp, dense, emb, W1, W2, ww, wb, b3, embb, dtail, W1b, W2b, wide);
    gemm1_8<<<256, 512, 0, stream>>>(
        sp, embb, dtail, W1b, b1, h1);
    // NOTE: grid stays 256 -- the split-K variant collapsed to redundant
    // compute (see comment in kernel); launching 512 would double work for
    // pure balancing data. Keep kh==0 path only: grid 256, kh=0.
    gemm_fused8<<<512, 512, 0, stream>>>(
        h1, W2b, b2, W3, wide, BATCH, HDIM, 1024, HDIM);
    sigmoid_kernel<<<BATCH / 256, 256, 0, stream>>>(wide, out);
}

// Round 8
// 186.231 us; speedup vs baseline: 1.0104x; 1.0104x over previous
//
#include <hip/hip_runtime.h>
#include <stdint.h>

// ---------------------------------------------------------------------------
// WideAndDeep: B=16384, F=3, C=256, D=64, H=1024, ND=13
// R22: gemm2 B operands moved OFF the LDS port: fragments loaded directly
// global->VGPR (plain C++ loads; compiler emits exact counted vmcnt, incl.
// the async A-stage loads in the same FIFO). Diagnosis: per-phase cost is
// ~1300cyc at any grid size (R21); LDS traffic per phase (48KB reads A x4 /
// B x2 redundancy + 16KB stage writes) / 85B/clk = 600-750cyc = the wall.
// B frag values are bit-identical to the LDS path (n*K + kt + s*32 + lad*8,
// no swizzle) -> absmax must stay exactly 0.00390625. A path unchanged
// (LDS-staged, swizzled, VM0 at p4/p8 drains only the 4 A-stage loads,
// 3-phase lead). LDS 128KB -> 64KB. gemm1/prep/sigmoid = R18 (159.1us best).
// ---------------------------------------------------------------------------

#define BATCH 16384
#define HDIM 1024
#define K1 256
#define DEEP_IN 205

typedef short bf16x8 __attribute__((ext_vector_type(8)));
typedef float f32x4 __attribute__((ext_vector_type(4)));
typedef uint16_t u16x8 __attribute__((ext_vector_type(8)));
typedef uint16_t u16x4 __attribute__((ext_vector_type(4)));

__device__ __forceinline__ uint16_t f2bf(float f) {
    uint32_t x;
    __builtin_memcpy(&x, &f, 4);
    uint32_t r = (x + 0x7fffu + ((x >> 16) & 1u)) >> 16;
    return (uint16_t)r;
}

__device__ __forceinline__ void async_ld16(const uint16_t* g, uint16_t* l) {
    __builtin_amdgcn_global_load_lds(
        (const __attribute__((address_space(1))) uint32_t*)g,
        (__attribute__((address_space(3))) uint32_t*)l, 16, 0, 0);
}

// ---------------------------------------------------------------------------
// prep: everything the GEMMs need, one elementwise kernel (R18 form).
// ---------------------------------------------------------------------------
__global__ __launch_bounds__(256) void prep_kernel(
    const int* __restrict__ sp, const float* __restrict__ dense,
    const float* __restrict__ emb, const float* __restrict__ W1,
    const float* __restrict__ W2, const float* __restrict__ ww,
    const float* __restrict__ wb, const float* __restrict__ b3,
    uint16_t* __restrict__ embb, uint16_t* __restrict__ dtail,
    uint16_t* __restrict__ W1b, uint16_t* __restrict__ W2b,
    float* __restrict__ wide)
{
    const int bid = blockIdx.x;
    const int tid = threadIdx.x;
    if (bid < 24) {                        // ---- emb -> bf16 (3*256*64 = 49152)
        int k = bid * 256 + tid;           // < 6144 vec8
        const float* src = emb + (size_t)k * 8;
        float4 v0 = *(const float4*)src;
        float4 v1 = *(const float4*)(src + 4);
        u16x8 o;
        o[0] = f2bf(v0.x); o[1] = f2bf(v0.y); o[2] = f2bf(v0.z); o[3] = f2bf(v0.w);
        o[4] = f2bf(v1.x); o[5] = f2bf(v1.y); o[6] = f2bf(v1.z); o[7] = f2bf(v1.w);
        *(u16x8*)(embb + (size_t)k * 8) = o;
    } else if (bid < 536) {                // ---- dense tail [16384][64]
        int idx = (bid - 24) * 256 + tid;  // < 131072 vec8
        int b = idx >> 3, c0 = (idx & 7) * 8;
        u16x8 o;
#pragma unroll
        for (int t = 0; t < 8; t++) {
            int c = c0 + t;
            o[t] = (c < 13) ? f2bf(dense[b * 13 + c]) : (uint16_t)0;
        }
        *(u16x8*)(dtail + (size_t)b * 64 + c0) = o;
    } else if (bid < 664) {                // ---- W1 convert, 205 -> 256
        int idx = (bid - 536) * 256 + tid;     // < 32768
        int n = idx >> 5, c0 = (idx & 31) * 8;
        u16x8 o;
#pragma unroll
        for (int t = 0; t < 8; t++) {
            int c = c0 + t;
            o[t] = (c < DEEP_IN) ? f2bf(W1[n * DEEP_IN + c]) : (uint16_t)0;
        }
        *(u16x8*)(W1b + (size_t)n * K1 + c0) = o;
    } else if (bid < 1176) {               // ---- W2 convert (x8)
        int k = (bid - 664) * 256 + tid;       // < 131072
        const float* src = W2 + (size_t)k * 8;
        float4 v0 = *(const float4*)src;
        float4 v1 = *(const float4*)(src + 4);
        u16x8 o;
        o[0] = f2bf(v0.x); o[1] = f2bf(v0.y); o[2] = f2bf(v0.z); o[3] = f2bf(v0.w);
        o[4] = f2bf(v1.x); o[5] = f2bf(v1.y); o[6] = f2bf(v1.z); o[7] = f2bf(v1.w);
        *(u16x8*)(W2b + (size_t)k * 8) = o;
    } else {                               // ---- wide path (+ b3 seed)
        int b = (bid - 1176) * 256 + tid;      // < 16384
        int s0 = sp[b * 3], s1 = sp[b * 3 + 1], s2 = sp[b * 3 + 2];
        float w = wb[0] + b3[0];
        w += ww[s0] + ww[256 + s1] + ww[512 + s2];
        w += ww[768    + s0 * 3 + s1];
        w += ww[66304  + s0 * 3 + s2];
        w += ww[131840 + s1 * 3 + s2];
        w += ww[197376 + (s0 * 3 + s1) * 3 + s2];
        const float* wd = ww + 16974592;
        float acc2 = 0.f;
#pragma unroll
        for (int j = 0; j < 13; j++) acc2 += dense[b * 13 + j] * wd[j];
        wide[b] = w + acc2;
    }
}

// ---------------------------------------------------------------------------
// Shared 8-phase GEMM machinery (R16/R18 proven).
// ---------------------------------------------------------------------------
#define BAR8() do { asm volatile("" ::: "memory");                             \
    __builtin_amdgcn_s_barrier();                                              \
    asm volatile("" ::: "memory"); } while (0)
#define VM4() asm volatile("s_waitcnt vmcnt(4)" ::: "memory")
#define VM0() asm volatile("s_waitcnt vmcnt(0)" ::: "memory")

#define LDA8(base, msub) do {                                                  \
    _Pragma("unroll") for (int mt = 0; mt < 4; mt++) {                         \
        int ro_ = (base) + ((msub) * 64 + mt * 16) * 64;                       \
        af[mt][0] = *(const bf16x8*)&lds[ro_ + kc0];                           \
        af[mt][1] = *(const bf16x8*)&lds[ro_ + kc1];                           \
    } } while (0)

#define LDB8(dst, base, nsub) do {                                             \
    _Pragma("unroll") for (int nt = 0; nt < 2; nt++) {                         \
        int ro_ = (base) + ((nsub) * 32 + nt * 16) * 64;                       \
        dst[nt][0] = *(const bf16x8*)&lds[ro_ + kc0];                          \
        dst[nt][1] = *(const bf16x8*)&lds[ro_ + kc1];                          \
    } } while (0)

#define MM8(msub, nsub, BF) do {                                               \
    __builtin_amdgcn_s_setprio(1);                                             \
    _Pragma("unroll") for (int mt = 0; mt < 4; mt++)                           \
    _Pragma("unroll") for (int nt = 0; nt < 2; nt++) {                         \
        acc[(msub)*4+mt][(nsub)*2+nt] = __builtin_amdgcn_mfma_f32_16x16x32_bf16( \
            af[mt][0], BF[nt][0], acc[(msub)*4+mt][(nsub)*2+nt], 0, 0, 0);     \
        acc[(msub)*4+mt][(nsub)*2+nt] = __builtin_amdgcn_mfma_f32_16x16x32_bf16( \
            af[mt][1], BF[nt][1], acc[(msub)*4+mt][(nsub)*2+nt], 0, 0, 0);     \
    }                                                                          \
    __builtin_amdgcn_s_setprio(0); } while (0)

#define GEMM8_DECLS(BID)                                                       \
    const int tid = threadIdx.x;                                               \
    const int lane = tid & 63, wave = tid >> 6;                                \
    const int wm = wave >> 2, wn = wave & 3;                                   \
    const int id = (BID);                                                      \
    const int wg = (id & 7) * 32 + (id >> 3);                                  \
    const int by = wg >> 2, bx = wg & 3;                                       \
    const int bm = by * 256, bn = bx * 256;                                    \
    const int lam = lane & 15, lad = lane >> 4;                                \
    const int sw = (lane & 7) << 4;                                            \
    const int kc0 = ((lad * 16) ^ sw) >> 1;                                    \
    const int kc1 = ((64 + lad * 16) ^ sw) >> 1;                               \
    const int aBE = wm * 8192 + lam * 64;                                      \
    const int aBO = aBE + 16384;                                               \
    const int bBE = 32768 + (wn >> 1) * 8192 + ((wn & 1) * 64 + lam) * 64;     \
    const int bBO = bBE + 16384;                                               \
    const int trow = tid >> 3;                                                 \
    const int csel = ((tid & 7) ^ (trow & 7)) << 3;

// R16 main loop for gemm1 (LDS-staged A and B).
#define GEMM8_MAIN()                                                           \
    f32x4 acc[8][4];                                                           \
    _Pragma("unroll") for (int i = 0; i < 8; i++)                              \
        _Pragma("unroll") for (int j = 0; j < 4; j++) acc[i][j] = (f32x4)0.f;  \
    bf16x8 af[4][2], bf0[2][2], bf1[2][2];                                     \
    const int NT = K >> 6;                                                     \
    const int NI = K >> 7;                                                     \
    STG8A(0, 0, 0);     STG8A(0, 1, 0);                                        \
    STG8B(32768, 0, 0); STG8B(32768, 1, 0);                                    \
    STG8B(49152, 0, 64); STG8B(49152, 1, 64);                                  \
    VM4();                                                                     \
    BAR8();                                                                    \
    for (int it = 0; it < NI; ++it) {                                          \
        const int k1 = (2 * it + 1) * 64;                                      \
        const int t2 = 2 * it + 2, t3 = 2 * it + 3;                            \
        const int k2 = (t2 < NT ? t2 : 0) * 64;                                \
        const int k3 = (t3 < NT ? t3 : 0) * 64;                                \
        LDA8(aBE, 0); LDB8(bf0, bBE, 0); STG8A(16384, 0, k1);                  \
        BAR8(); MM8(0, 0, bf0); BAR8();                                        \
        LDB8(bf1, bBE, 1); STG8A(16384, 1, k1);                                \
        BAR8(); MM8(0, 1, bf1); BAR8();                                        \
        LDA8(aBE, 1); STG8B(32768, 0, k2);                                     \
        BAR8(); MM8(1, 1, bf1); BAR8();                                        \
        STG8B(32768, 1, k2);                                                   \
        BAR8(); MM8(1, 0, bf0); VM4(); BAR8();                                 \
        LDA8(aBO, 0); LDB8(bf0, bBO, 0); STG8A(0, 0, k2);                      \
        BAR8(); MM8(0, 0, bf0); BAR8();                                        \
        LDB8(bf1, bBO, 1); STG8A(0, 1, k2);                                    \
        BAR8(); MM8(0, 1, bf1); BAR8();                                        \
        LDA8(aBO, 1); STG8B(49152, 0, k3);                                     \
        BAR8(); MM8(1, 1, bf1); BAR8();                                        \
        STG8B(49152, 1, k3);                                                   \
        BAR8(); MM8(1, 0, bf0); VM4(); BAR8();                                 \
    }

// ---------------------------------------------------------------------------
// gemm1_8: h1 = relu(deep_x @ W1b^T + b1), K=256 (zero-padded). R18 form.
// ---------------------------------------------------------------------------
#define ASRC1(pkv, h2, kt) ((kt) < 192                                         \
    ? (embb + (((kt) >> 6) << 14)                                              \
            + ((int)(((pkv) >> (((kt) >> 6) << 3)) & 255u) << 6) + csel)       \
    : (dtail + (size_t)(b0 + (h2) * 64) * 64 + csel))

#define STG8A(regoff, h, kt) do {                                              \
    async_ld16(ASRC1(PK##h##_0, 2*(h), kt),                                    \
               &lds[(regoff) + (h) * 8192 + wave * 512]);                      \
    async_ld16(ASRC1(PK##h##_1, 2*(h)+1, kt),                                  \
               &lds[(regoff) + (h) * 8192 + 4096 + wave * 512]);               \
} while (0)

#define STG8B(regoff, h, kt) do {                                              \
    const uint16_t* g_ = bRow + (size_t)((h) * 128) * (size_t)K + (kt);        \
    async_ld16(g_, &lds[(regoff) + (h) * 8192 + wave * 512]);                  \
    async_ld16(g_ + (size_t)64 * (size_t)K,                                    \
               &lds[(regoff) + (h) * 8192 + 4096 + wave * 512]);               \
} while (0)

__global__ __launch_bounds__(512, 2) void gemm1_8(
    const int* __restrict__ sp, const uint16_t* __restrict__ embb,
    const uint16_t* __restrict__ dtail, const uint16_t* __restrict__ Bw,
    const float* __restrict__ bias, uint16_t* __restrict__ C)
{
    __shared__ __align__(16) uint16_t lds[65536];   // 128 KiB
    GEMM8_DECLS(blockIdx.x)
    const int K = K1;
    const int b0 = bm + trow;
    const uint32_t PK0_0 = (uint32_t)sp[(b0      ) * 3] |
                           ((uint32_t)sp[(b0      ) * 3 + 1] << 8) |
                           ((uint32_t)sp[(b0      ) * 3 + 2] << 16);
    const uint32_t PK0_1 = (uint32_t)sp[(b0 +  64) * 3] |
                           ((uint32_t)sp[(b0 +  64) * 3 + 1] << 8) |
                           ((uint32_t)sp[(b0 +  64) * 3 + 2] << 16);
    const uint32_t PK1_0 = (uint32_t)sp[(b0 + 128) * 3] |
                           ((uint32_t)sp[(b0 + 128) * 3 + 1] << 8) |
                           ((uint32_t)sp[(b0 + 128) * 3 + 2] << 16);
    const uint32_t PK1_1 = (uint32_t)sp[(b0 + 192) * 3] |
                           ((uint32_t)sp[(b0 + 192) * 3 + 1] << 8) |
                           ((uint32_t)sp[(b0 + 192) * 3 + 2] << 16);
    const int prow = 4 * (trow & 15) + (trow >> 4);
    const uint16_t* bRow = Bw + (size_t)(bn + prow) * K + csel;
    VM0();   // drain sp loads: counted-vmcnt FIFO must start clean
    GEMM8_MAIN()

    float bv[4];
#pragma unroll
    for (int jn = 0; jn < 4; jn++) bv[jn] = bias[bn + wn * 64 + 4 * lam + jn];
#pragma unroll
    for (int im = 0; im < 8; im++) {
#pragma unroll
        for (int r = 0; r < 4; r++) {
            int m = bm + wm * 128 + im * 16 + lad * 4 + r;
            u16x4 o;
#pragma unroll
            for (int jn = 0; jn < 4; jn++)
                o[jn] = f2bf(fmaxf(acc[im][jn][r] + bv[jn], 0.f));
            *(u16x4*)&C[(size_t)m * HDIM + bn + wn * 64 + 4 * lam] = o;
        }
    }
}

#undef STG8A
#undef STG8B

// ---------------------------------------------------------------------------
// gemm_fused8 (R22): A LDS-staged (E/O regions, 64KB), B fragments loaded
// directly global->VGPR (L2-resident W2b; values bit-identical to the LDS
// path: elem = n*K + kt + s*32 + lad*8, n = bn+wn*64+nsub*32+nt*16+lam).
// Per iter: p1 {load B.E frags (8), stage A.O (4), LDA(m0)}, p2 {MM m0n1},
// p3 {LDA(m1)}, p4 {MM m1n0, VM0 drains A.O (3-phase lead)}, p5-p8 mirror
// with B.O / next A.E. Compiler inserts exact counted vmcnt for B frags
// (tracks async A-stage loads in the same FIFO). Epilogue: shfl-reduce +
// atomicAdd (R18 proven).
// ---------------------------------------------------------------------------
#define STA2(regoff, h, kt) do {                                               \
    const uint16_t* g_ = aRow + (size_t)((h) * 128) * (size_t)K + (kt);        \
    async_ld16(g_, &lds[(regoff) + (h) * 8192 + wave * 512]);                  \
    async_ld16(g_ + (size_t)64 * (size_t)K,                                    \
               &lds[(regoff) + (h) * 8192 + 4096 + wave * 512]);               \
} while (0)

#define LDBG0(d, kt) do {                                                      \
    d[0][0] = *(const bf16x8*)(bN0 + (kt));                                    \
    d[0][1] = *(const bf16x8*)(bN0 + (kt) + 32);                               \
    d[1][0] = *(const bf16x8*)(bN1 + (kt));                                    \
    d[1][1] = *(const bf16x8*)(bN1 + (kt) + 32);                               \
} while (0)

#define LDBG1(d, kt) do {                                                      \
    d[0][0] = *(const bf16x8*)(bN2 + (kt));                                    \
    d[0][1] = *(const bf16x8*)(bN2 + (kt) + 32);                               \
    d[1][0] = *(const bf16x8*)(bN3 + (kt));                                    \
    d[1][1] = *(const bf16x8*)(bN3 + (kt) + 32);                               \
} while (0)

__global__ __launch_bounds__(512, 2) void gemm_fused8(
    const uint16_t* __restrict__ A, const uint16_t* __restrict__ Bw,
    const float* __restrict__ bias, const float* __restrict__ W3,
    float* __restrict__ outacc, int M, int N, int K)
{
    __shared__ __align__(16) uint16_t lds[32768];   // 64 KiB: A only (E/O)
    GEMM8_DECLS(blockIdx.x)
    (void)bBE; (void)bBO;
    const uint16_t* aRow = A + (size_t)(bm + trow) * K + csel;
    // B fragment base pointers: nt/nsub cols, lane k-offset lad*8
    const uint16_t* bN0 = Bw + (size_t)(bn + wn * 64 + lam) * K + lad * 8;
    const uint16_t* bN1 = bN0 + (size_t)16 * K;
    const uint16_t* bN2 = bN0 + (size_t)32 * K;
    const uint16_t* bN3 = bN0 + (size_t)48 * K;

    f32x4 acc[8][4];
#pragma unroll
    for (int i = 0; i < 8; i++)
#pragma unroll
        for (int j = 0; j < 4; j++) acc[i][j] = (f32x4)0.f;
    bf16x8 af[4][2], bf0[2][2], bf1[2][2];
    const int NI = K >> 7;

    // prologue: stage A.E(tile0) both halves, drain, barrier
    STA2(0, 0, 0); STA2(0, 1, 0);
    VM0();
    BAR8();

    for (int it = 0; it < NI; ++it) {
        const int ktE = it << 7, ktO = ktE + 64;
        const int ktN = (it + 1 < NI) ? (ktE + 128) : 0;   // wrap dead
        // p1: B.E frags first (so their waits don't drain A stages),
        //     then stage A.O (this iter), LDA(m0); MM(m0,n0)
        LDBG0(bf0, ktE); LDBG1(bf1, ktE);
        STA2(16384, 0, ktO); STA2(16384, 1, ktO);
        LDA8(aBE, 0);
        BAR8(); MM8(0, 0, bf0); BAR8();
        // p2: MM(m0,n1)
        BAR8(); MM8(0, 1, bf1); BAR8();
        // p3: LDA(m1); MM(m1,n1)
        LDA8(aBE, 1);
        BAR8(); MM8(1, 1, bf1); BAR8();
        // p4: MM(m1,n0); drain A.O stages (3-phase lead), barrier
        BAR8(); MM8(1, 0, bf0); VM0(); BAR8();
        // p5: B.O frags; stage next A.E; LDA(m0); MM(m0,n0)
        LDBG0(bf0, ktO); LDBG1(bf1, ktO);
        STA2(0, 0, ktN); STA2(0, 1, ktN);
        LDA8(aBO, 0);
        BAR8(); MM8(0, 0, bf0); BAR8();
        // p6: MM(m0,n1)
        BAR8(); MM8(0, 1, bf1); BAR8();
        // p7: LDA(m1); MM(m1,n1)
        LDA8(aBO, 1);
        BAR8(); MM8(1, 1, bf1); BAR8();
        // p8: MM(m1,n0); drain A.E stages, barrier
        BAR8(); MM8(1, 0, bf0); VM0(); BAR8();
    }

    float bv[4], w3v[4];
#pragma unroll
    for (int jn = 0; jn < 4; jn++) {
        int n = bn + wn * 64 + jn * 16 + lam;
        bv[jn] = bias[n];
        w3v[jn] = W3[n];
    }
#pragma unroll
    for (int im = 0; im < 8; im++) {
#pragma unroll
        for (int r = 0; r < 4; r++) {
            float pt = 0.f;
#pragma unroll
            for (int jn = 0; jn < 4; jn++)
                pt += fmaxf(acc[im][jn][r] + bv[jn], 0.f) * w3v[jn];
            pt += __shfl_xor(pt, 1);
            pt += __shfl_xor(pt, 2);
            pt += __shfl_xor(pt, 4);
            pt += __shfl_xor(pt, 8);
            if (lam == 0) {
                int m = bm + wm * 128 + im * 16 + lad * 4 + r;
                atomicAdd(&outacc[m], pt);
            }
        }
    }
}

#undef STA2
#undef LDBG0
#undef LDBG1

// ---------------------------------------------------------------------------
// Sigmoid over the accumulated logits. Grid 64 x 256.
// ---------------------------------------------------------------------------
__global__ __launch_bounds__(256) void sigmoid_kernel(
    const float* __restrict__ outacc, float* __restrict__ out)
{
    int b = blockIdx.x * 256 + threadIdx.x;
    out[b] = 1.f / (1.f + __expf(-outacc[b]));
}

// ---------------------------------------------------------------------------
extern "C" void kernel_launch(void* const* d_in, const int* in_sizes, int n_in,
                              void* d_out, int out_size, void* d_ws, size_t ws_size,
                              hipStream_t stream) {
    const int*   sp    = (const int*)d_in[0];
    const float* dense = (const float*)d_in[1];
    const float* ww    = (const float*)d_in[2];
    const float* wb    = (const float*)d_in[3];
    const float* emb   = (const float*)d_in[4];
    const float* W1    = (const float*)d_in[5];
    const float* b1    = (const float*)d_in[6];
    const float* W2    = (const float*)d_in[7];
    const float* b2    = (const float*)d_in[8];
    const float* W3    = (const float*)d_in[9];
    const float* b3    = (const float*)d_in[10];
    float* out = (float*)d_out;

    char* ws = (char*)d_ws;
    float*    wide  = (float*)ws;                      //     65,536 B
    uint16_t* embb  = (uint16_t*)(ws + 65536);         //     98,304 B (3x256x64)
    uint16_t* dtail = (uint16_t*)(ws + 163840);        //  2,097,152 B (16384x64)
    uint16_t* W1b   = (uint16_t*)(ws + 2260992);       //    524,288 B (1024x256)
    uint16_t* W2b   = (uint16_t*)(ws + 2785280);       //  2,097,152 B
    uint16_t* h1    = (uint16_t*)(ws + 4882432);       // 33,554,432 B -> 38,436,864 total

    prep_kernel<<<1240, 256, 0, stream>>>(
        sp, dense, emb, W1, W2, ww, wb, b3, embb, dtail, W1b, W2b, wide);
    gemm1_8<<<256, 512, 0, stream>>>(
        sp, embb, dtail, W1b, b1, h1);
    gemm_fused8<<<256, 512, 0, stream>>>(
        h1, W2b, b2, W3, wide, BATCH, HDIM, HDIM);
    sigmoid_kernel<<<BATCH / 256, 256, 0, stream>>>(wide, out);
}

// Round 9
// 175.458 us; speedup vs baseline: 1.0724x; 1.0614x over previous
//
#include <hip/hip_runtime.h>
#include <stdint.h>

// ---------------------------------------------------------------------------
// WideAndDeep: B=16384, F=3, C=256, D=64, H=1024, ND=13
// R23: revert R22 (B-direct regressed: uncoalesced 16B/lane gathers).
// gemm2 = 256x128 tiles, 512 blocks = 2 overlapping rounds (R21 measured
// 34.6us/round when rounds overlap vs 42.3 single-round -> captures the
// ~8us prologue/tail overlap without redundant work). Same proven per-phase
// content: {ds_reads | 3 stage calls | BAR | 16 MFMA | BAR}, 4 phases/iter,
// vmcnt(2) at even phases. B frags read once per K-tile, reused both MM
// phases. LDS 96KiB: AE=0 AO=16384 BE=32768 BO=40960 (elems); regions
// [rows][64 cols] row-major, row-XOR swizzle (r&7)<<4 bytes (pre-swizzled
// source csel, linear dest, swizzled read kc0/kc1 -- rule 21).
// FIFO (3 calls/phase: p1 A.O[0..2]; p2 A.O[3],B.E'[0,1]; p3 A.E'[0..2];
// p4 A.E'[3],B.O'[0,1]): VM2@p2 retires A.O[0..3] (read p3); VM2@p4
// retires B.E'+A.E' (read next p1); next VM2@p2 retires B.O' (read p3).
// Prologue 8 calls (A.E0 x4, B.E0 x2, B.O0 x2) + VM2 retires first 6.
// WAR: stages issue behind the closing barrier of the last reading phase.
// gemm1/prep/sigmoid = R18 (159.1us best).
// ---------------------------------------------------------------------------

#define BATCH 16384
#define HDIM 1024
#define K1 256
#define DEEP_IN 205

typedef short bf16x8 __attribute__((ext_vector_type(8)));
typedef float f32x4 __attribute__((ext_vector_type(4)));
typedef uint16_t u16x8 __attribute__((ext_vector_type(8)));
typedef uint16_t u16x4 __attribute__((ext_vector_type(4)));

__device__ __forceinline__ uint16_t f2bf(float f) {
    uint32_t x;
    __builtin_memcpy(&x, &f, 4);
    uint32_t r = (x + 0x7fffu + ((x >> 16) & 1u)) >> 16;
    return (uint16_t)r;
}

__device__ __forceinline__ void async_ld16(const uint16_t* g, uint16_t* l) {
    __builtin_amdgcn_global_load_lds(
        (const __attribute__((address_space(1))) uint32_t*)g,
        (__attribute__((address_space(3))) uint32_t*)l, 16, 0, 0);
}

// ---------------------------------------------------------------------------
// prep: everything the GEMMs need, one elementwise kernel (R18 form).
// ---------------------------------------------------------------------------
__global__ __launch_bounds__(256) void prep_kernel(
    const int* __restrict__ sp, const float* __restrict__ dense,
    const float* __restrict__ emb, const float* __restrict__ W1,
    const float* __restrict__ W2, const float* __restrict__ ww,
    const float* __restrict__ wb, const float* __restrict__ b3,
    uint16_t* __restrict__ embb, uint16_t* __restrict__ dtail,
    uint16_t* __restrict__ W1b, uint16_t* __restrict__ W2b,
    float* __restrict__ wide)
{
    const int bid = blockIdx.x;
    const int tid = threadIdx.x;
    if (bid < 24) {                        // ---- emb -> bf16 (3*256*64 = 49152)
        int k = bid * 256 + tid;           // < 6144 vec8
        const float* src = emb + (size_t)k * 8;
        float4 v0 = *(const float4*)src;
        float4 v1 = *(const float4*)(src + 4);
        u16x8 o;
        o[0] = f2bf(v0.x); o[1] = f2bf(v0.y); o[2] = f2bf(v0.z); o[3] = f2bf(v0.w);
        o[4] = f2bf(v1.x); o[5] = f2bf(v1.y); o[6] = f2bf(v1.z); o[7] = f2bf(v1.w);
        *(u16x8*)(embb + (size_t)k * 8) = o;
    } else if (bid < 536) {                // ---- dense tail [16384][64]
        int idx = (bid - 24) * 256 + tid;  // < 131072 vec8
        int b = idx >> 3, c0 = (idx & 7) * 8;
        u16x8 o;
#pragma unroll
        for (int t = 0; t < 8; t++) {
            int c = c0 + t;
            o[t] = (c < 13) ? f2bf(dense[b * 13 + c]) : (uint16_t)0;
        }
        *(u16x8*)(dtail + (size_t)b * 64 + c0) = o;
    } else if (bid < 664) {                // ---- W1 convert, 205 -> 256
        int idx = (bid - 536) * 256 + tid;     // < 32768
        int n = idx >> 5, c0 = (idx & 31) * 8;
        u16x8 o;
#pragma unroll
        for (int t = 0; t < 8; t++) {
            int c = c0 + t;
            o[t] = (c < DEEP_IN) ? f2bf(W1[n * DEEP_IN + c]) : (uint16_t)0;
        }
        *(u16x8*)(W1b + (size_t)n * K1 + c0) = o;
    } else if (bid < 1176) {               // ---- W2 convert (x8)
        int k = (bid - 664) * 256 + tid;       // < 131072
        const float* src = W2 + (size_t)k * 8;
        float4 v0 = *(const float4*)src;
        float4 v1 = *(const float4*)(src + 4);
        u16x8 o;
        o[0] = f2bf(v0.x); o[1] = f2bf(v0.y); o[2] = f2bf(v0.z); o[3] = f2bf(v0.w);
        o[4] = f2bf(v1.x); o[5] = f2bf(v1.y); o[6] = f2bf(v1.z); o[7] = f2bf(v1.w);
        *(u16x8*)(W2b + (size_t)k * 8) = o;
    } else {                               // ---- wide path (+ b3 seed)
        int b = (bid - 1176) * 256 + tid;      // < 16384
        int s0 = sp[b * 3], s1 = sp[b * 3 + 1], s2 = sp[b * 3 + 2];
        float w = wb[0] + b3[0];
        w += ww[s0] + ww[256 + s1] + ww[512 + s2];
        w += ww[768    + s0 * 3 + s1];
        w += ww[66304  + s0 * 3 + s2];
        w += ww[131840 + s1 * 3 + s2];
        w += ww[197376 + (s0 * 3 + s1) * 3 + s2];
        const float* wd = ww + 16974592;
        float acc2 = 0.f;
#pragma unroll
        for (int j = 0; j < 13; j++) acc2 += dense[b * 13 + j] * wd[j];
        wide[b] = w + acc2;
    }
}

// ---------------------------------------------------------------------------
// Shared 8-phase GEMM machinery (R16/R18 proven) -- used by gemm1.
// ---------------------------------------------------------------------------
#define BAR8() do { asm volatile("" ::: "memory");                             \
    __builtin_amdgcn_s_barrier();                                              \
    asm volatile("" ::: "memory"); } while (0)
#define VM4() asm volatile("s_waitcnt vmcnt(4)" ::: "memory")
#define VM2() asm volatile("s_waitcnt vmcnt(2)" ::: "memory")
#define VM0() asm volatile("s_waitcnt vmcnt(0)" ::: "memory")

#define LDA8(base, msub) do {                                                  \
    _Pragma("unroll") for (int mt = 0; mt < 4; mt++) {                         \
        int ro_ = (base) + ((msub) * 64 + mt * 16) * 64;                       \
        af[mt][0] = *(const bf16x8*)&lds[ro_ + kc0];                           \
        af[mt][1] = *(const bf16x8*)&lds[ro_ + kc1];                           \
    } } while (0)

#define LDB8(dst, base, nsub) do {                                             \
    _Pragma("unroll") for (int nt = 0; nt < 2; nt++) {                         \
        int ro_ = (base) + ((nsub) * 32 + nt * 16) * 64;                       \
        dst[nt][0] = *(const bf16x8*)&lds[ro_ + kc0];                          \
        dst[nt][1] = *(const bf16x8*)&lds[ro_ + kc1];                          \
    } } while (0)

#define MM8(msub, nsub, BF) do {                                               \
    __builtin_amdgcn_s_setprio(1);                                             \
    _Pragma("unroll") for (int mt = 0; mt < 4; mt++)                           \
    _Pragma("unroll") for (int nt = 0; nt < 2; nt++) {                         \
        acc[(msub)*4+mt][(nsub)*2+nt] = __builtin_amdgcn_mfma_f32_16x16x32_bf16( \
            af[mt][0], BF[nt][0], acc[(msub)*4+mt][(nsub)*2+nt], 0, 0, 0);     \
        acc[(msub)*4+mt][(nsub)*2+nt] = __builtin_amdgcn_mfma_f32_16x16x32_bf16( \
            af[mt][1], BF[nt][1], acc[(msub)*4+mt][(nsub)*2+nt], 0, 0, 0);     \
    }                                                                          \
    __builtin_amdgcn_s_setprio(0); } while (0)

#define GEMM8_DECLS()                                                          \
    const int tid = threadIdx.x;                                               \
    const int lane = tid & 63, wave = tid >> 6;                                \
    const int wm = wave >> 2, wn = wave & 3;                                   \
    const int id = blockIdx.x;                                                 \
    const int wg = (id & 7) * 32 + (id >> 3);                                  \
    const int by = wg >> 2, bx = wg & 3;                                       \
    const int bm = by * 256, bn = bx * 256;                                    \
    const int lam = lane & 15, lad = lane >> 4;                                \
    const int sw = (lane & 7) << 4;                                            \
    const int kc0 = ((lad * 16) ^ sw) >> 1;                                    \
    const int kc1 = ((64 + lad * 16) ^ sw) >> 1;                               \
    const int aBE = wm * 8192 + lam * 64;                                      \
    const int aBO = aBE + 16384;                                               \
    const int bBE = 32768 + (wn >> 1) * 8192 + ((wn & 1) * 64 + lam) * 64;     \
    const int bBO = bBE + 16384;                                               \
    const int trow = tid >> 3;                                                 \
    const int csel = ((tid & 7) ^ (trow & 7)) << 3;

#define GEMM8_MAIN()                                                           \
    f32x4 acc[8][4];                                                           \
    _Pragma("unroll") for (int i = 0; i < 8; i++)                              \
        _Pragma("unroll") for (int j = 0; j < 4; j++) acc[i][j] = (f32x4)0.f;  \
    bf16x8 af[4][2], bf0[2][2], bf1[2][2];                                     \
    const int NT = K >> 6;                                                     \
    const int NI = K >> 7;                                                     \
    STG8A(0, 0, 0);     STG8A(0, 1, 0);                                        \
    STG8B(32768, 0, 0); STG8B(32768, 1, 0);                                    \
    STG8B(49152, 0, 64); STG8B(49152, 1, 64);                                  \
    VM4();                                                                     \
    BAR8();                                                                    \
    for (int it = 0; it < NI; ++it) {                                          \
        const int k1 = (2 * it + 1) * 64;                                      \
        const int t2 = 2 * it + 2, t3 = 2 * it + 3;                            \
        const int k2 = (t2 < NT ? t2 : 0) * 64;                                \
        const int k3 = (t3 < NT ? t3 : 0) * 64;                                \
        LDA8(aBE, 0); LDB8(bf0, bBE, 0); STG8A(16384, 0, k1);                  \
        BAR8(); MM8(0, 0, bf0); BAR8();                                        \
        LDB8(bf1, bBE, 1); STG8A(16384, 1, k1);                                \
        BAR8(); MM8(0, 1, bf1); BAR8();                                        \
        LDA8(aBE, 1); STG8B(32768, 0, k2);                                     \
        BAR8(); MM8(1, 1, bf1); BAR8();                                        \
        STG8B(32768, 1, k2);                                                   \
        BAR8(); MM8(1, 0, bf0); VM4(); BAR8();                                 \
        LDA8(aBO, 0); LDB8(bf0, bBO, 0); STG8A(0, 0, k2);                      \
        BAR8(); MM8(0, 0, bf0); BAR8();                                        \
        LDB8(bf1, bBO, 1); STG8A(0, 1, k2);                                    \
        BAR8(); MM8(0, 1, bf1); BAR8();                                        \
        LDA8(aBO, 1); STG8B(49152, 0, k3);                                     \
        BAR8(); MM8(1, 1, bf1); BAR8();                                        \
        STG8B(49152, 1, k3);                                                   \
        BAR8(); MM8(1, 0, bf0); VM4(); BAR8();                                 \
    }

// ---------------------------------------------------------------------------
// gemm1_8: h1 = relu(deep_x @ W1b^T + b1), K=256 (zero-padded). R18 form.
// ---------------------------------------------------------------------------
#define ASRC1(pkv, h2, kt) ((kt) < 192                                         \
    ? (embb + (((kt) >> 6) << 14)                                              \
            + ((int)(((pkv) >> (((kt) >> 6) << 3)) & 255u) << 6) + csel)       \
    : (dtail + (size_t)(b0 + (h2) * 64) * 64 + csel))

#define STG8A(regoff, h, kt) do {                                              \
    async_ld16(ASRC1(PK##h##_0, 2*(h), kt),                                    \
               &lds[(regoff) + (h) * 8192 + wave * 512]);                      \
    async_ld16(ASRC1(PK##h##_1, 2*(h)+1, kt),                                  \
               &lds[(regoff) + (h) * 8192 + 4096 + wave * 512]);               \
} while (0)

#define STG8B(regoff, h, kt) do {                                              \
    const uint16_t* g_ = bRow + (size_t)((h) * 128) * (size_t)K + (kt);        \
    async_ld16(g_, &lds[(regoff) + (h) * 8192 + wave * 512]);                  \
    async_ld16(g_ + (size_t)64 * (size_t)K,                                    \
               &lds[(regoff) + (h) * 8192 + 4096 + wave * 512]);               \
} while (0)

__global__ __launch_bounds__(512, 2) void gemm1_8(
    const int* __restrict__ sp, const uint16_t* __restrict__ embb,
    const uint16_t* __restrict__ dtail, const uint16_t* __restrict__ Bw,
    const float* __restrict__ bias, uint16_t* __restrict__ C)
{
    __shared__ __align__(16) uint16_t lds[65536];   // 128 KiB
    GEMM8_DECLS()
    const int K = K1;
    const int b0 = bm + trow;
    const uint32_t PK0_0 = (uint32_t)sp[(b0      ) * 3] |
                           ((uint32_t)sp[(b0      ) * 3 + 1] << 8) |
                           ((uint32_t)sp[(b0      ) * 3 + 2] << 16);
    const uint32_t PK0_1 = (uint32_t)sp[(b0 +  64) * 3] |
                           ((uint32_t)sp[(b0 +  64) * 3 + 1] << 8) |
                           ((uint32_t)sp[(b0 +  64) * 3 + 2] << 16);
    const uint32_t PK1_0 = (uint32_t)sp[(b0 + 128) * 3] |
                           ((uint32_t)sp[(b0 + 128) * 3 + 1] << 8) |
                           ((uint32_t)sp[(b0 + 128) * 3 + 2] << 16);
    const uint32_t PK1_1 = (uint32_t)sp[(b0 + 192) * 3] |
                           ((uint32_t)sp[(b0 + 192) * 3 + 1] << 8) |
                           ((uint32_t)sp[(b0 + 192) * 3 + 2] << 16);
    const int prow = 4 * (trow & 15) + (trow >> 4);
    const uint16_t* bRow = Bw + (size_t)(bn + prow) * K + csel;
    VM0();   // drain sp loads: counted-vmcnt FIFO must start clean
    GEMM8_MAIN()

    float bv[4];
#pragma unroll
    for (int jn = 0; jn < 4; jn++) bv[jn] = bias[bn + wn * 64 + 4 * lam + jn];
#pragma unroll
    for (int im = 0; im < 8; im++) {
#pragma unroll
        for (int r = 0; r < 4; r++) {
            int m = bm + wm * 128 + im * 16 + lad * 4 + r;
            u16x4 o;
#pragma unroll
            for (int jn = 0; jn < 4; jn++)
                o[jn] = f2bf(fmaxf(acc[im][jn][r] + bv[jn], 0.f));
            *(u16x4*)&C[(size_t)m * HDIM + bn + wn * 64 + 4 * lam] = o;
        }
    }
}

#undef STG8A
#undef STG8B

// ---------------------------------------------------------------------------
// gemm_fused8 (R23): 256x128 tile, 512 blocks (2 overlapping rounds).
// 8 waves 2m x 4n, wave tile 128x32, BK=64, 4 phases/iter, vmcnt(2) at
// even phases. LDS 96KiB: AE=0 AO=16384 BE=32768 BO=40960 (elems).
// B frags (4 ds_reads) loaded once per K-tile, reused in both MM phases.
// Epilogue: relu(acc+b2).W3, shfl-reduce over 16 lanes, atomicAdd.
// ---------------------------------------------------------------------------
#define STA3(reg, c, kt) async_ld16(                                           \
    aRow + (size_t)((c) * 64) * (size_t)K + (kt),                              \
    &lds[(reg) + (c) * 4096 + wave * 512])

#define STB3(reg, c, kt) async_ld16(                                           \
    bRow + (size_t)((c) * 64) * (size_t)K + (kt),                              \
    &lds[(reg) + (c) * 4096 + wave * 512])

#define LDAH(reg, msub) do {                                                   \
    _Pragma("unroll") for (int mt = 0; mt < 4; mt++) {                         \
        int ro_ = (reg) + aRd + ((msub) * 64 + mt * 16) * 64;                  \
        af[mt][0] = *(const bf16x8*)&lds[ro_ + kc0];                           \
        af[mt][1] = *(const bf16x8*)&lds[ro_ + kc1];                           \
    } } while (0)

#define LDBH(reg) do {                                                         \
    _Pragma("unroll") for (int nt = 0; nt < 2; nt++) {                         \
        int ro_ = (reg) + bRd + nt * 1024;                                     \
        bf[nt][0] = *(const bf16x8*)&lds[ro_ + kc0];                           \
        bf[nt][1] = *(const bf16x8*)&lds[ro_ + kc1];                           \
    } } while (0)

#define MMH(msub) do {                                                         \
    __builtin_amdgcn_s_setprio(1);                                             \
    _Pragma("unroll") for (int mt = 0; mt < 4; mt++)                           \
    _Pragma("unroll") for (int nt = 0; nt < 2; nt++) {                         \
        acc[(msub)*4+mt][nt] = __builtin_amdgcn_mfma_f32_16x16x32_bf16(        \
            af[mt][0], bf[nt][0], acc[(msub)*4+mt][nt], 0, 0, 0);              \
        acc[(msub)*4+mt][nt] = __builtin_amdgcn_mfma_f32_16x16x32_bf16(        \
            af[mt][1], bf[nt][1], acc[(msub)*4+mt][nt], 0, 0, 0);              \
    }                                                                          \
    __builtin_amdgcn_s_setprio(0); } while (0)

__global__ __launch_bounds__(512, 2) void gemm_fused8(
    const uint16_t* __restrict__ A, const uint16_t* __restrict__ Bw,
    const float* __restrict__ bias, const float* __restrict__ W3,
    float* __restrict__ outacc, int M, int N, int K)
{
    __shared__ __align__(16) uint16_t lds[49152];   // 96 KiB
    const int tid = threadIdx.x;
    const int lane = tid & 63, wave = tid >> 6;
    const int wm = wave >> 2, wn = wave & 3;
    const int id = blockIdx.x;
    const int wg = (id & 7) * 64 + (id >> 3);       // XCD swizzle (512 wgs)
    const int by = wg >> 3, bx = wg & 7;
    const int bm = by * 256, bn = bx * 128;
    const int lam = lane & 15, lad = lane >> 4;
    const int sw = (lane & 7) << 4;
    const int kc0 = ((lad * 16) ^ sw) >> 1;
    const int kc1 = ((64 + lad * 16) ^ sw) >> 1;
    const int aRd = (wm * 128 + lam) * 64;          // A region lane base
    const int bRd = (wn * 32 + lam) * 64;           // B region lane base
    const int trow = tid >> 3;
    const int csel = ((tid & 7) ^ (trow & 7)) << 3;
    const uint16_t* aRow = A + (size_t)(bm + trow) * K + csel;
    const uint16_t* bRow = Bw + (size_t)(bn + trow) * K + csel;

    f32x4 acc[8][2];
#pragma unroll
    for (int i = 0; i < 8; i++)
#pragma unroll
        for (int j = 0; j < 2; j++) acc[i][j] = (f32x4)0.f;
    bf16x8 af[4][2], bf[2][2];
    const int NT = K >> 6;                          // 16 K-tiles
    const int NI = K >> 7;                          // 8 iterations

    // prologue: A.E0 (4 calls), B.E0 (2), B.O0 = tile1 (2); retire first 6
    STA3(0, 0, 0); STA3(0, 1, 0); STA3(0, 2, 0); STA3(0, 3, 0);
    STB3(32768, 0, 0); STB3(32768, 1, 0);
    STB3(40960, 0, 64); STB3(40960, 1, 64);
    VM2();
    BAR8();

    for (int it = 0; it < NI; ++it) {
        const int ktO = (it << 7) + 64;             // tile 2it+1
        const int tE = 2 * it + 2, tO = 2 * it + 3;
        const int ktNE = (tE < NT ? tE : 0) << 6;   // wrap dead, in-bounds
        const int ktNO = (tO < NT ? tO : 0) << 6;
        // p1: read E(m0)+B.E; stage A.O[0..2]
        LDAH(0, 0); LDBH(32768);
        STA3(16384, 0, ktO); STA3(16384, 1, ktO); STA3(16384, 2, ktO);
        BAR8(); MMH(0); BAR8();
        // p2: read E(m1); stage A.O[3], B.E'[0,1]; VM2 retires A.O[0..3]
        LDAH(0, 1);
        STA3(16384, 3, ktO); STB3(32768, 0, ktNE); STB3(32768, 1, ktNE);
        BAR8(); MMH(1); VM2(); BAR8();
        // p3: read O(m0)+B.O; stage A.E'[0..2]
        LDAH(16384, 0); LDBH(40960);
        STA3(0, 0, ktNE); STA3(0, 1, ktNE); STA3(0, 2, ktNE);
        BAR8(); MMH(0); BAR8();
        // p4: read O(m1); stage A.E'[3], B.O'[0,1]; VM2 retires B.E'+A.E'
        LDAH(16384, 1);
        STA3(0, 3, ktNE); STB3(40960, 0, ktNO); STB3(40960, 1, ktNO);
        BAR8(); MMH(1); VM2(); BAR8();
    }

    float bv[2], w3v[2];
#pragma unroll
    for (int nt = 0; nt < 2; nt++) {
        int n = bn + wn * 32 + nt * 16 + lam;
        bv[nt] = bias[n];
        w3v[nt] = W3[n];
    }
#pragma unroll
    for (int im = 0; im < 8; im++) {
#pragma unroll
        for (int r = 0; r < 4; r++) {
            float pt = 0.f;
#pragma unroll
            for (int nt = 0; nt < 2; nt++)
                pt += fmaxf(acc[im][nt][r] + bv[nt], 0.f) * w3v[nt];
            pt += __shfl_xor(pt, 1);
            pt += __shfl_xor(pt, 2);
            pt += __shfl_xor(pt, 4);
            pt += __shfl_xor(pt, 8);
            if (lam == 0) {
                int m = bm + wm * 128 + im * 16 + lad * 4 + r;
                atomicAdd(&outacc[m], pt);
            }
        }
    }
}

#undef STA3
#undef STB3
#undef LDAH
#undef LDBH
#undef MMH

// ---------------------------------------------------------------------------
// Sigmoid over the accumulated logits. Grid 64 x 256.
// ---------------------------------------------------------------------------
__global__ __launch_bounds__(256) void sigmoid_kernel(
    const float* __restrict__ outacc, float* __restrict__ out)
{
    int b = blockIdx.x * 256 + threadIdx.x;
    out[b] = 1.f / (1.f + __expf(-outacc[b]));
}

// ---------------------------------------------------------------------------
extern "C" void kernel_launch(void* const* d_in, const int* in_sizes, int n_in,
                              void* d_out, int out_size, void* d_ws, size_t ws_size,
                              hipStream_t stream) {
    const int*   sp    = (const int*)d_in[0];
    const float* dense = (const float*)d_in[1];
    const float* ww    = (const float*)d_in[2];
    const float* wb    = (const float*)d_in[3];
    const float* emb   = (const float*)d_in[4];
    const float* W1    = (const float*)d_in[5];
    const float* b1    = (const float*)d_in[6];
    const float* W2    = (const float*)d_in[7];
    const float* b2    = (const float*)d_in[8];
    const float* W3    = (const float*)d_in[9];
    const float* b3    = (const float*)d_in[10];
    float* out = (float*)d_out;

    char* ws = (char*)d_ws;
    float*    wide  = (float*)ws;                      //     65,536 B
    uint16_t* embb  = (uint16_t*)(ws + 65536);         //     98,304 B (3x256x64)
    uint16_t* dtail = (uint16_t*)(ws + 163840);        //  2,097,152 B (16384x64)
    uint16_t* W1b   = (uint16_t*)(ws + 2260992);       //    524,288 B (1024x256)
    uint16_t* W2b   = (uint16_t*)(ws + 2785280);       //  2,097,152 B
    uint16_t* h1    = (uint16_t*)(ws + 4882432);       // 33,554,432 B -> 38,436,864 total

    prep_kernel<<<1240, 256, 0, stream>>>(
        sp, dense, emb, W1, W2, ww, wb, b3, embb, dtail, W1b, W2b, wide);
    gemm1_8<<<256, 512, 0, stream>>>(
        sp, embb, dtail, W1b, b1, h1);
    gemm_fused8<<<512, 512, 0, stream>>>(
        h1, W2b, b2, W3, wide, BATCH, HDIM, HDIM);
    sigmoid_kernel<<<BATCH / 256, 256, 0, stream>>>(wide, out);
}

// Round 11
// 159.371 us; speedup vs baseline: 1.1806x; 1.1009x over previous
//
#include <hip/hip_runtime.h>
#include <stdint.h>

// ---------------------------------------------------------------------------
// WideAndDeep: B=16384, F=3, C=256, D=64, H=1024, ND=13
// R25: resubmit of R24 (pure R18 revert, best measured 159.1us) -- R24's
// bench was an infra failure (container died twice), not a kernel issue.
// Ledger: R19 sigmoid-fusion +1.7, R20 ring-4 null, R21 2x-grid slower,
// R22 B-direct -50%, R23 N-split -23%. 256x256 tile, 8-wave, BK=64,
// 8-phase counted-vmcnt schedule is a sharply local optimum at ~1100-1300
// cyc/phase; LDS read pattern at the b128 8-round minimum; HBM 8% of peak.
// gemm1 = emb-gather A-staging (L2-resident 96KB table) + B-col
// permutation for packed u16x4 stores.
// 8-phase stage order per iter:
//   p1:A.O.h0  p2:A.O.h1  p3:B.E.h0  p4:B.E.h1[vmcnt4]
//   p5:A.E.h0  p6:A.E.h1  p7:B.O.h0  p8:B.O.h1[vmcnt4]
// FIFO: vmcnt(4)@p4 retires {B.O prev, A.O}; vmcnt(4)@p8 retires {B.E,A.E}.
// Wrap loads (last iter) re-read tile 0 (cache-absorbed) keeping pacing
// uniform (R17: tail peeling regresses).
// ---------------------------------------------------------------------------

#define BATCH 16384
#define HDIM 1024
#define K1 256
#define DEEP_IN 205

typedef short bf16x8 __attribute__((ext_vector_type(8)));
typedef float f32x4 __attribute__((ext_vector_type(4)));
typedef uint16_t u16x8 __attribute__((ext_vector_type(8)));
typedef uint16_t u16x4 __attribute__((ext_vector_type(4)));

__device__ __forceinline__ uint16_t f2bf(float f) {
    uint32_t x;
    __builtin_memcpy(&x, &f, 4);
    uint32_t r = (x + 0x7fffu + ((x >> 16) & 1u)) >> 16;
    return (uint16_t)r;
}

__device__ __forceinline__ void async_ld16(const uint16_t* g, uint16_t* l) {
    __builtin_amdgcn_global_load_lds(
        (const __attribute__((address_space(1))) uint32_t*)g,
        (__attribute__((address_space(3))) uint32_t*)l, 16, 0, 0);
}

// ---------------------------------------------------------------------------
// prep: everything the GEMMs need, one elementwise kernel.
//   [0, 24)      : emb -> emb_bf16 (49152 elems, x8)
//   [24, 536)    : dtail [B][64] bf16: cols 0..12 = dense, 13..63 = 0 (x8)
//   [536, 664)   : W1 -> bf16, 205 -> 256 K-pad (x8)
//   [664, 1176)  : W2 -> bf16 (x8)
//   [1176, 1240) : wide path (sparse gathers + dense dot) + b3 seed
// ---------------------------------------------------------------------------
__global__ __launch_bounds__(256) void prep_kernel(
    const int* __restrict__ sp, const float* __restrict__ dense,
    const float* __restrict__ emb, const float* __restrict__ W1,
    const float* __restrict__ W2, const float* __restrict__ ww,
    const float* __restrict__ wb, const float* __restrict__ b3,
    uint16_t* __restrict__ embb, uint16_t* __restrict__ dtail,
    uint16_t* __restrict__ W1b, uint16_t* __restrict__ W2b,
    float* __restrict__ wide)
{
    const int bid = blockIdx.x;
    const int tid = threadIdx.x;
    if (bid < 24) {                        // ---- emb -> bf16 (3*256*64 = 49152)
        int k = bid * 256 + tid;           // < 6144 vec8
        const float* src = emb + (size_t)k * 8;
        float4 v0 = *(const float4*)src;
        float4 v1 = *(const float4*)(src + 4);
        u16x8 o;
        o[0] = f2bf(v0.x); o[1] = f2bf(v0.y); o[2] = f2bf(v0.z); o[3] = f2bf(v0.w);
        o[4] = f2bf(v1.x); o[5] = f2bf(v1.y); o[6] = f2bf(v1.z); o[7] = f2bf(v1.w);
        *(u16x8*)(embb + (size_t)k * 8) = o;
    } else if (bid < 536) {                // ---- dense tail [16384][64]
        int idx = (bid - 24) * 256 + tid;  // < 131072 vec8
        int b = idx >> 3, c0 = (idx & 7) * 8;
        u16x8 o;
#pragma unroll
        for (int t = 0; t < 8; t++) {
            int c = c0 + t;
            o[t] = (c < 13) ? f2bf(dense[b * 13 + c]) : (uint16_t)0;
        }
        *(u16x8*)(dtail + (size_t)b * 64 + c0) = o;
    } else if (bid < 664) {                // ---- W1 convert, 205 -> 256
        int idx = (bid - 536) * 256 + tid;     // < 32768
        int n = idx >> 5, c0 = (idx & 31) * 8;
        u16x8 o;
#pragma unroll
        for (int t = 0; t < 8; t++) {
            int c = c0 + t;
            o[t] = (c < DEEP_IN) ? f2bf(W1[n * DEEP_IN + c]) : (uint16_t)0;
        }
        *(u16x8*)(W1b + (size_t)n * K1 + c0) = o;
    } else if (bid < 1176) {               // ---- W2 convert (x8)
        int k = (bid - 664) * 256 + tid;       // < 131072
        const float* src = W2 + (size_t)k * 8;
        float4 v0 = *(const float4*)src;
        float4 v1 = *(const float4*)(src + 4);
        u16x8 o;
        o[0] = f2bf(v0.x); o[1] = f2bf(v0.y); o[2] = f2bf(v0.z); o[3] = f2bf(v0.w);
        o[4] = f2bf(v1.x); o[5] = f2bf(v1.y); o[6] = f2bf(v1.z); o[7] = f2bf(v1.w);
        *(u16x8*)(W2b + (size_t)k * 8) = o;
    } else {                               // ---- wide path (+ b3 seed)
        int b = (bid - 1176) * 256 + tid;      // < 16384
        int s0 = sp[b * 3], s1 = sp[b * 3 + 1], s2 = sp[b * 3 + 2];
        float w = wb[0] + b3[0];
        w += ww[s0] + ww[256 + s1] + ww[512 + s2];
        w += ww[768    + s0 * 3 + s1];
        w += ww[66304  + s0 * 3 + s2];
        w += ww[131840 + s1 * 3 + s2];
        w += ww[197376 + (s0 * 3 + s1) * 3 + s2];
        const float* wd = ww + 16974592;
        float acc2 = 0.f;
#pragma unroll
        for (int j = 0; j < 13; j++) acc2 += dense[b * 13 + j] * wd[j];
        wide[b] = w + acc2;
    }
}

// ---------------------------------------------------------------------------
// Shared 8-phase GEMM core. 256x256 tile, 8 waves 2m x 4n, wave tile 128x64,
// BK=64, 128 KiB LDS (2 K-tile dbuf). LDS element map: AE=0 AO=16384
// BE=32768 BO=49152; each region [2 halves][128 rows][64 cols], row r's
// column bytes XOR-swizzled by (r&7)<<4 (inverse-swizzled global source,
// linear global_load_lds dest). Raw s_barrier; vmcnt(4) only at p4 & p8.
// Per-kernel STG8A/STG8B macros supply the staging source addresses.
// ---------------------------------------------------------------------------
#define BAR8() do { asm volatile("" ::: "memory");                             \
    __builtin_amdgcn_s_barrier();                                              \
    asm volatile("" ::: "memory"); } while (0)
#define VM4() asm volatile("s_waitcnt vmcnt(4)" ::: "memory")
#define VM0() asm volatile("s_waitcnt vmcnt(0)" ::: "memory")

#define LDA8(base, msub) do {                                                  \
    _Pragma("unroll") for (int mt = 0; mt < 4; mt++) {                         \
        int ro_ = (base) + ((msub) * 64 + mt * 16) * 64;                       \
        af[mt][0] = *(const bf16x8*)&lds[ro_ + kc0];                           \
        af[mt][1] = *(const bf16x8*)&lds[ro_ + kc1];                           \
    } } while (0)

#define LDB8(dst, base, nsub) do {                                             \
    _Pragma("unroll") for (int nt = 0; nt < 2; nt++) {                         \
        int ro_ = (base) + ((nsub) * 32 + nt * 16) * 64;                       \
        dst[nt][0] = *(const bf16x8*)&lds[ro_ + kc0];                          \
        dst[nt][1] = *(const bf16x8*)&lds[ro_ + kc1];                          \
    } } while (0)

#define MM8(msub, nsub, BF) do {                                               \
    __builtin_amdgcn_s_setprio(1);                                             \
    _Pragma("unroll") for (int mt = 0; mt < 4; mt++)                           \
    _Pragma("unroll") for (int nt = 0; nt < 2; nt++) {                         \
        acc[(msub)*4+mt][(nsub)*2+nt] = __builtin_amdgcn_mfma_f32_16x16x32_bf16( \
            af[mt][0], BF[nt][0], acc[(msub)*4+mt][(nsub)*2+nt], 0, 0, 0);     \
        acc[(msub)*4+mt][(nsub)*2+nt] = __builtin_amdgcn_mfma_f32_16x16x32_bf16( \
            af[mt][1], BF[nt][1], acc[(msub)*4+mt][(nsub)*2+nt], 0, 0, 0);     \
    }                                                                          \
    __builtin_amdgcn_s_setprio(0); } while (0)

#define GEMM8_DECLS()                                                          \
    const int tid = threadIdx.x;                                               \
    const int lane = tid & 63, wave = tid >> 6;                                \
    const int wm = wave >> 2, wn = wave & 3;                                   \
    const int id = blockIdx.x;                                                 \
    const int wg = (id & 7) * 32 + (id >> 3);                                  \
    const int by = wg >> 2, bx = wg & 3;                                       \
    const int bm = by * 256, bn = bx * 256;                                    \
    const int lam = lane & 15, lad = lane >> 4;                                \
    const int sw = (lane & 7) << 4;                                            \
    const int kc0 = ((lad * 16) ^ sw) >> 1;                                    \
    const int kc1 = ((64 + lad * 16) ^ sw) >> 1;                               \
    const int aBE = wm * 8192 + lam * 64;                                      \
    const int aBO = aBE + 16384;                                               \
    const int bBE = 32768 + (wn >> 1) * 8192 + ((wn & 1) * 64 + lam) * 64;     \
    const int bBO = bBE + 16384;                                               \
    const int trow = tid >> 3;                                                 \
    const int csel = ((tid & 7) ^ (trow & 7)) << 3;

// R16 main loop: uniform 8-phase schedule, wrap dead-loads keep pacing.
#define GEMM8_MAIN()                                                           \
    f32x4 acc[8][4];                                                           \
    _Pragma("unroll") for (int i = 0; i < 8; i++)                              \
        _Pragma("unroll") for (int j = 0; j < 4; j++) acc[i][j] = (f32x4)0.f;  \
    bf16x8 af[4][2], bf0[2][2], bf1[2][2];                                     \
    const int NT = K >> 6;                                                     \
    const int NI = K >> 7;                                                     \
    STG8A(0, 0, 0);     STG8A(0, 1, 0);                                        \
    STG8B(32768, 0, 0); STG8B(32768, 1, 0);                                    \
    STG8B(49152, 0, 64); STG8B(49152, 1, 64);                                  \
    VM4();                                                                     \
    BAR8();                                                                    \
    for (int it = 0; it < NI; ++it) {                                          \
        const int k1 = (2 * it + 1) * 64;                                      \
        const int t2 = 2 * it + 2, t3 = 2 * it + 3;                            \
        const int k2 = (t2 < NT ? t2 : 0) * 64;                                \
        const int k3 = (t3 < NT ? t3 : 0) * 64;                                \
        LDA8(aBE, 0); LDB8(bf0, bBE, 0); STG8A(16384, 0, k1);                  \
        BAR8(); MM8(0, 0, bf0); BAR8();                                        \
        LDB8(bf1, bBE, 1); STG8A(16384, 1, k1);                                \
        BAR8(); MM8(0, 1, bf1); BAR8();                                        \
        LDA8(aBE, 1); STG8B(32768, 0, k2);                                     \
        BAR8(); MM8(1, 1, bf1); BAR8();                                        \
        STG8B(32768, 1, k2);                                                   \
        BAR8(); MM8(1, 0, bf0); VM4(); BAR8();                                 \
        LDA8(aBO, 0); LDB8(bf0, bBO, 0); STG8A(0, 0, k2);                      \
        BAR8(); MM8(0, 0, bf0); BAR8();                                        \
        LDB8(bf1, bBO, 1); STG8A(0, 1, k2);                                    \
        BAR8(); MM8(0, 1, bf1); BAR8();                                        \
        LDA8(aBO, 1); STG8B(49152, 0, k3);                                     \
        BAR8(); MM8(1, 1, bf1); BAR8();                                        \
        STG8B(49152, 1, k3);                                                   \
        BAR8(); MM8(1, 0, bf0); VM4(); BAR8();                                 \
    }

// ---------------------------------------------------------------------------
// gemm1_8: h1 = relu(deep_x @ W1b^T + b1), K=256 (zero-padded).
// A-staging sources: k-tiles 0..2 gather from emb_bf16 [f][256][64] (row via
// packed sp scalar PKh_j, selected by (kt>>6)*8 bit shift -- pure ALU, no
// runtime-indexed arrays); k-tile 3 reads dtail [B][64]. B rows staged
// permuted (prow = 4*(t&15) + (t>>4)) so lane lam's acc cols jn map to
// n = bn + wn*64 + 4*lam + jn -> natural-layout u16x4 packed stores.
// ---------------------------------------------------------------------------
#define ASRC1(pkv, h2, kt) ((kt) < 192                                         \
    ? (embb + (((kt) >> 6) << 14)                                              \
            + ((int)(((pkv) >> (((kt) >> 6) << 3)) & 255u) << 6) + csel)       \
    : (dtail + (size_t)(b0 + (h2) * 64) * 64 + csel))

#define STG8A(regoff, h, kt) do {                                              \
    async_ld16(ASRC1(PK##h##_0, 2*(h), kt),                                    \
               &lds[(regoff) + (h) * 8192 + wave * 512]);                      \
    async_ld16(ASRC1(PK##h##_1, 2*(h)+1, kt),                                  \
               &lds[(regoff) + (h) * 8192 + 4096 + wave * 512]);               \
} while (0)

#define STG8B(regoff, h, kt) do {                                              \
    const uint16_t* g_ = bRow + (size_t)((h) * 128) * (size_t)K + (kt);        \
    async_ld16(g_, &lds[(regoff) + (h) * 8192 + wave * 512]);                  \
    async_ld16(g_ + (size_t)64 * (size_t)K,                                    \
               &lds[(regoff) + (h) * 8192 + 4096 + wave * 512]);               \
} while (0)

__global__ __launch_bounds__(512, 2) void gemm1_8(
    const int* __restrict__ sp, const uint16_t* __restrict__ embb,
    const uint16_t* __restrict__ dtail, const uint16_t* __restrict__ Bw,
    const float* __restrict__ bias, uint16_t* __restrict__ C)
{
    __shared__ __align__(16) uint16_t lds[65536];   // 128 KiB
    GEMM8_DECLS()
    const int K = K1;
    const int b0 = bm + trow;
    // pack sparse ids for the 4 A-row slots (rows b0 + {0,64,128,192})
    const uint32_t PK0_0 = (uint32_t)sp[(b0      ) * 3] |
                           ((uint32_t)sp[(b0      ) * 3 + 1] << 8) |
                           ((uint32_t)sp[(b0      ) * 3 + 2] << 16);
    const uint32_t PK0_1 = (uint32_t)sp[(b0 +  64) * 3] |
                           ((uint32_t)sp[(b0 +  64) * 3 + 1] << 8) |
                           ((uint32_t)sp[(b0 +  64) * 3 + 2] << 16);
    const uint32_t PK1_0 = (uint32_t)sp[(b0 + 128) * 3] |
                           ((uint32_t)sp[(b0 + 128) * 3 + 1] << 8) |
                           ((uint32_t)sp[(b0 + 128) * 3 + 2] << 16);
    const uint32_t PK1_1 = (uint32_t)sp[(b0 + 192) * 3] |
                           ((uint32_t)sp[(b0 + 192) * 3 + 1] << 8) |
                           ((uint32_t)sp[(b0 + 192) * 3 + 2] << 16);
    const int prow = 4 * (trow & 15) + (trow >> 4);
    const uint16_t* bRow = Bw + (size_t)(bn + prow) * K + csel;
    VM0();   // drain sp loads: counted-vmcnt FIFO must start clean
    GEMM8_MAIN()

    float bv[4];
#pragma unroll
    for (int jn = 0; jn < 4; jn++) bv[jn] = bias[bn + wn * 64 + 4 * lam + jn];
#pragma unroll
    for (int im = 0; im < 8; im++) {
#pragma unroll
        for (int r = 0; r < 4; r++) {
            int m = bm + wm * 128 + im * 16 + lad * 4 + r;
            u16x4 o;
#pragma unroll
            for (int jn = 0; jn < 4; jn++)
                o[jn] = f2bf(fmaxf(acc[im][jn][r] + bv[jn], 0.f));
            *(u16x4*)&C[(size_t)m * HDIM + bn + wn * 64 + 4 * lam] = o;
        }
    }
}

#undef STG8A
#undef STG8B

// ---------------------------------------------------------------------------
// gemm_fused8: per-row partial of relu(acc + b2) . W3 -> atomicAdd(outacc).
// (B staged unpermuted; n-permutation irrelevant to the reduction.)
// ---------------------------------------------------------------------------
#define STG8A(regoff, h, kt) do {                                              \
    const uint16_t* g_ = aRow + (size_t)((h) * 128) * (size_t)K + (kt);        \
    async_ld16(g_, &lds[(regoff) + (h) * 8192 + wave * 512]);                  \
    async_ld16(g_ + (size_t)64 * (size_t)K,                                    \
               &lds[(regoff) + (h) * 8192 + 4096 + wave * 512]);               \
} while (0)

#define STG8B(regoff, h, kt) do {                                              \
    const uint16_t* g_ = bRow + (size_t)((h) * 128) * (size_t)K + (kt);        \
    async_ld16(g_, &lds[(regoff) + (h) * 8192 + wave * 512]);                  \
    async_ld16(g_ + (size_t)64 * (size_t)K,                                    \
               &lds[(regoff) + (h) * 8192 + 4096 + wave * 512]);               \
} while (0)

__global__ __launch_bounds__(512, 2) void gemm_fused8(
    const uint16_t* __restrict__ A, const uint16_t* __restrict__ Bw,
    const float* __restrict__ bias, const float* __restrict__ W3,
    float* __restrict__ outacc, int M, int N, int K)
{
    __shared__ __align__(16) uint16_t lds[65536];   // 128 KiB
    GEMM8_DECLS()
    const uint16_t* aRow = A + (size_t)(bm + trow) * K + csel;
    const uint16_t* bRow = Bw + (size_t)(bn + trow) * K + csel;
    GEMM8_MAIN()

    float bv[4], w3v[4];
#pragma unroll
    for (int jn = 0; jn < 4; jn++) {
        int n = bn + wn * 64 + jn * 16 + lam;
        bv[jn] = bias[n];
        w3v[jn] = W3[n];
    }
#pragma unroll
    for (int im = 0; im < 8; im++) {
#pragma unroll
        for (int r = 0; r < 4; r++) {
            float pt = 0.f;
#pragma unroll
            for (int jn = 0; jn < 4; jn++)
                pt += fmaxf(acc[im][jn][r] + bv[jn], 0.f) * w3v[jn];
            pt += __shfl_xor(pt, 1);
            pt += __shfl_xor(pt, 2);
            pt += __shfl_xor(pt, 4);
            pt += __shfl_xor(pt, 8);
            if (lam == 0) {
                int m = bm + wm * 128 + im * 16 + lad * 4 + r;
                atomicAdd(&outacc[m], pt);
            }
        }
    }
}

#undef STG8A
#undef STG8B

// ---------------------------------------------------------------------------
// Sigmoid over the accumulated logits. Grid 64 x 256.
// ---------------------------------------------------------------------------
__global__ __launch_bounds__(256) void sigmoid_kernel(
    const float* __restrict__ outacc, float* __restrict__ out)
{
    int b = blockIdx.x * 256 + threadIdx.x;
    out[b] = 1.f / (1.f + __expf(-outacc[b]));
}

// ---------------------------------------------------------------------------
extern "C" void kernel_launch(void* const* d_in, const int* in_sizes, int n_in,
                              void* d_out, int out_size, void* d_ws, size_t ws_size,
                              hipStream_t stream) {
    const int*   sp    = (const int*)d_in[0];
    const float* dense = (const float*)d_in[1];
    const float* ww    = (const float*)d_in[2];
    const float* wb    = (const float*)d_in[3];
    const float* emb   = (const float*)d_in[4];
    const float* W1    = (const float*)d_in[5];
    const float* b1    = (const float*)d_in[6];
    const float* W2    = (const float*)d_in[7];
    const float* b2    = (const float*)d_in[8];
    const float* W3    = (const float*)d_in[9];
    const float* b3    = (const float*)d_in[10];
    float* out = (float*)d_out;

    char* ws = (char*)d_ws;
    float*    wide  = (float*)ws;                      //     65,536 B
    uint16_t* embb  = (uint16_t*)(ws + 65536);         //     98,304 B (3x256x64)
    uint16_t* dtail = (uint16_t*)(ws + 163840);        //  2,097,152 B (16384x64)
    uint16_t* W1b   = (uint16_t*)(ws + 2260992);       //    524,288 B (1024x256)
    uint16_t* W2b   = (uint16_t*)(ws + 2785280);       //  2,097,152 B
    uint16_t* h1    = (uint16_t*)(ws + 4882432);       // 33,554,432 B -> 38,436,864 total

    prep_kernel<<<1240, 256, 0, stream>>>(
        sp, dense, emb, W1, W2, ww, wb, b3, embb, dtail, W1b, W2b, wide);
    gemm1_8<<<256, 512, 0, stream>>>(
        sp, embb, dtail, W1b, b1, h1);
    gemm_fused8<<<256, 512, 0, stream>>>(
        h1, W2b, b2, W3, wide, BATCH, HDIM, HDIM);
    sigmoid_kernel<<<BATCH / 256, 256, 0, stream>>>(wide, out);
}